// Round 1
// baseline (585.724 us; speedup 1.0000x reference)
//
#include <hip/hip_runtime.h>
#include <math.h>

// Soft-Viterbi structured decoding: B=32, T=512, N=128, fp32.
// One block per batch element b; 4 waves; lane owns states (2l, 2l+1).
// Forward: alpha recurrence with scalar shift c=alpha[0] (readlane, no reduce).
//   e_t = exp(a_t - c_{t+1}) stored INTO out[b][t][:] (scratch-in-output).
//   c_t kept in LDS carr[].
// Backward: p_t = e_t * (q @ T^T), q[n] = p_{t+1}[n] * exp(em_{t+1}[n]-c_{t+2}) / e_{t+1}[n]
//   (exact reconstruction of 1/Z_t; no (T,B,N,N) backpointer tensor, no d_ws).

#define TT 512
#define BB 32
#define NN 128
#define EPSC 1e-10f

__device__ __forceinline__ float lane0_bcast(float v) {
  return __uint_as_float(__builtin_amdgcn_readlane(__float_as_uint(v), 0));
}

__global__ __launch_bounds__(256, 1)
void soft_viterbi_kernel(const float* __restrict__ trans,
                         const float* __restrict__ emis,
                         const float* __restrict__ prior,
                         float* __restrict__ out) {
  const int b    = blockIdx.x;
  const int tid  = threadIdx.x;
  const int w    = tid >> 6;       // wave 0..3: owns prev-chunk (fwd) / next-chunk (bwd) [32w,32w+32)
  const int lane = tid & 63;
  const int s0   = lane * 2;       // owned states (redundant across waves)
  const int s1   = s0 + 1;

  __shared__ __align__(16) float rowsum[NN];
  __shared__ __align__(16) float ebuf[NN];       // e (fwd) / q (bwd) broadcast buffer
  __shared__ __align__(16) float part[4][NN];    // per-wave partial sums
  __shared__ __align__(16) float carr[TT];       // per-step shift c_t

  const float2* emis2 = (const float2*)emis;
  float2* out2 = (float2*)out;
  const int eb = b * TT * (NN / 2);              // float2 index base for batch b

  // ---- row sums of clipped transition (row-normalization denominators) ----
  if (tid < NN) {
    const float4* row = (const float4*)(trans + tid * NN);
    float s = 0.f;
    #pragma unroll 8
    for (int j = 0; j < NN / 4; ++j) {
      float4 v = row[j];
      s += fmaxf(v.x, EPSC) + fmaxf(v.y, EPSC) + fmaxf(v.z, EPSC) + fmaxf(v.w, EPSC);
    }
    rowsum[tid] = s;
  }
  __syncthreads();

  // ---- forward transition fragment in VGPRs: tc{0,1}[k] = Tn[32w+k][s0/s1] ----
  float tc0[32], tc1[32];
  #pragma unroll
  for (int k = 0; k < 32; ++k) {
    const int p = 32 * w + k;
    const float inv = 1.0f / rowsum[p];
    float2 v = ((const float2*)(trans + p * NN))[lane];
    tc0[k] = fmaxf(v.x, EPSC) * inv;
    tc1[k] = fmaxf(v.y, EPSC) * inv;
  }
  // ---- backward fragment: tr{0,1}[k] = Tn[s0/s1][32w+k] ----
  float tr0[32], tr1[32];
  {
    const float inv0 = 1.0f / rowsum[s0];
    const float inv1 = 1.0f / rowsum[s1];
    const float4* r0 = (const float4*)(trans + s0 * NN + 32 * w);
    const float4* r1 = (const float4*)(trans + s1 * NN + 32 * w);
    #pragma unroll
    for (int k = 0; k < 8; ++k) {
      float4 v0 = r0[k], v1 = r1[k];
      tr0[4*k+0] = fmaxf(v0.x, EPSC) * inv0; tr0[4*k+1] = fmaxf(v0.y, EPSC) * inv0;
      tr0[4*k+2] = fmaxf(v0.z, EPSC) * inv0; tr0[4*k+3] = fmaxf(v0.w, EPSC) * inv0;
      tr1[4*k+0] = fmaxf(v1.x, EPSC) * inv1; tr1[4*k+1] = fmaxf(v1.y, EPSC) * inv1;
      tr1[4*k+2] = fmaxf(v1.z, EPSC) * inv1; tr1[4*k+3] = fmaxf(v1.w, EPSC) * inv1;
    }
  }

  // ---- init alpha ----
  float2 pv = ((const float2*)prior)[lane];
  float pr0 = fmaxf(pv.x, EPSC), pr1 = fmaxf(pv.y, EPSC);
  float psum = pr0 + pr1;
  #pragma unroll
  for (int m = 1; m < 64; m <<= 1) psum += __shfl_xor(psum, m, 64);
  const float lps = __logf(psum);
  float2 em0v = emis2[eb + lane];
  float a0 = __logf(pr0) - lps + em0v.x;
  float a1 = __logf(pr1) - lps + em0v.y;

  const bool writer = ((lane >> 4) == w);  // this wave's 16 lanes covering its 32-state chunk
  float2* ebuf2  = (float2*)ebuf;
  float2* partw2 = (float2*)&part[w][0];

  // ================= forward =================
  float2 em_pf = emis2[eb + (NN / 2) + lane];  // em for t=1
  float2 emc = em_pf;
  for (int t = 1; t < TT; ++t) {
    emc = em_pf;
    if (t + 1 < TT) em_pf = emis2[eb + (t + 1) * (NN / 2) + lane];  // prefetch
    const float c = lane0_bcast(a0);
    if (tid == 0) carr[t] = c;
    const float e0 = __expf(a0 - c);
    const float e1 = __expf(a1 - c);
    if (writer) ebuf2[lane] = make_float2(e0, e1);
    __syncthreads();
    float z0a = 0.f, z0b = 0.f, z1a = 0.f, z1b = 0.f;
    const float4* eb4 = (const float4*)&ebuf[32 * w];
    #pragma unroll
    for (int k = 0; k < 8; ++k) {
      float4 ev = eb4[k];   // broadcast read (all lanes same addr)
      z0a = fmaf(ev.x, tc0[4*k+0], z0a); z1a = fmaf(ev.x, tc1[4*k+0], z1a);
      z0b = fmaf(ev.y, tc0[4*k+1], z0b); z1b = fmaf(ev.y, tc1[4*k+1], z1b);
      z0a = fmaf(ev.z, tc0[4*k+2], z0a); z1a = fmaf(ev.z, tc1[4*k+2], z1a);
      z0b = fmaf(ev.w, tc0[4*k+3], z0b); z1b = fmaf(ev.w, tc1[4*k+3], z1b);
    }
    partw2[lane] = make_float2(z0a + z0b, z1a + z1b);
    __syncthreads();
    float2 pz0 = ((float2*)&part[0][0])[lane];
    float2 pz1 = ((float2*)&part[1][0])[lane];
    float2 pz2 = ((float2*)&part[2][0])[lane];
    float2 pz3 = ((float2*)&part[3][0])[lane];
    const float Z0 = (pz0.x + pz1.x) + (pz2.x + pz3.x);
    const float Z1 = (pz0.y + pz1.y) + (pz2.y + pz3.y);
    if (w == 0) out2[eb + (t - 1) * (NN / 2) + lane] = make_float2(e0, e1);  // stash e_{t-1}
    a0 = emc.x + __logf(Z0);
    a1 = emc.y + __logf(Z1);
  }
  const float2 emLast = emc;  // em_{T-1}

  // ---- final softmax: p_{T-1} ----
  float mx = fmaxf(a0, a1);
  #pragma unroll
  for (int m = 1; m < 64; m <<= 1) mx = fmaxf(mx, __shfl_xor(mx, m, 64));
  float x0 = __expf(a0 - mx), x1 = __expf(a1 - mx);
  float sm = x0 + x1;
  #pragma unroll
  for (int m = 1; m < 64; m <<= 1) sm += __shfl_xor(sm, m, 64);
  const float isum = 1.0f / sm;
  float p0 = x0 * isum, p1 = x1 * isum;
  if (w == 0) out2[eb + (TT - 1) * (NN / 2) + lane] = make_float2(p0, p1);

  __syncthreads();  // drain wave0's e-stores before cross-wave reads (vmcnt(0) at barrier)

  // ================= backward =================
  float2 e_pf = out2[eb + (TT - 2) * (NN / 2) + lane];  // e_{T-2}
  float2 em_bpf = make_float2(0.f, 0.f);
  float c_pf = 0.f;
  float rpe0 = 1.f, rpe1 = 1.f;  // 1/e_{t+1}
  for (int t = TT - 2; t >= 0; --t) {
    const float2 ec = e_pf;  // e_t
    float q0, q1;
    if (t == TT - 2) {
      // Z_{T-2}[n] = exp(a_{T-1}[n] - em_{T-1}[n]), a_{T-1} still in regs
      q0 = p0 * __expf(emLast.x - a0);
      q1 = p1 * __expf(emLast.y - a1);
    } else {
      // Z_t[n] = e_{t+1}[n] * exp(c_{t+2} - em_{t+1}[n])
      q0 = p0 * __expf(em_bpf.x - c_pf) * rpe0;
      q1 = p1 * __expf(em_bpf.y - c_pf) * rpe1;
    }
    if (t > 0) {  // prefetch for iter t-1
      e_pf   = out2[eb + (t - 1) * (NN / 2) + lane];  // e_{t-1}
      em_bpf = emis2[eb + t * (NN / 2) + lane];       // em_t  (= em_{(t-1)+1})
      c_pf   = carr[t + 1];                           // c_{(t-1)+2}
    }
    if (writer) ebuf2[lane] = make_float2(q0, q1);
    __syncthreads();
    float S0a = 0.f, S0b = 0.f, S1a = 0.f, S1b = 0.f;
    const float4* qb4 = (const float4*)&ebuf[32 * w];
    #pragma unroll
    for (int k = 0; k < 8; ++k) {
      float4 qv = qb4[k];
      S0a = fmaf(qv.x, tr0[4*k+0], S0a); S1a = fmaf(qv.x, tr1[4*k+0], S1a);
      S0b = fmaf(qv.y, tr0[4*k+1], S0b); S1b = fmaf(qv.y, tr1[4*k+1], S1b);
      S0a = fmaf(qv.z, tr0[4*k+2], S0a); S1a = fmaf(qv.z, tr1[4*k+2], S1a);
      S0b = fmaf(qv.w, tr0[4*k+3], S0b); S1b = fmaf(qv.w, tr1[4*k+3], S1b);
    }
    partw2[lane] = make_float2(S0a + S0b, S1a + S1b);
    __syncthreads();
    float2 ps0 = ((float2*)&part[0][0])[lane];
    float2 ps1 = ((float2*)&part[1][0])[lane];
    float2 ps2 = ((float2*)&part[2][0])[lane];
    float2 ps3 = ((float2*)&part[3][0])[lane];
    p0 = ec.x * ((ps0.x + ps1.x) + (ps2.x + ps3.x));
    p1 = ec.y * ((ps0.y + ps1.y) + (ps2.y + ps3.y));
    if (w == 0) out2[eb + t * (NN / 2) + lane] = make_float2(p0, p1);  // overwrite e_t with p_t
    // off-critical-path prep for next iter's q
    rpe0 = 1.0f / ec.x;
    rpe1 = 1.0f / ec.y;
  }
}

extern "C" void kernel_launch(void* const* d_in, const int* in_sizes, int n_in,
                              void* d_out, int out_size, void* d_ws, size_t ws_size,
                              hipStream_t stream) {
  (void)in_sizes; (void)n_in; (void)d_ws; (void)ws_size; (void)out_size;
  const float* trans = (const float*)d_in[0];
  const float* emis  = (const float*)d_in[1];
  const float* prior = (const float*)d_in[2];
  float* out = (float*)d_out;
  soft_viterbi_kernel<<<dim3(BB), dim3(256), 0, stream>>>(trans, emis, prior, out);
}

// Round 2
// 581.555 us; speedup vs baseline: 1.0072x; 1.0072x over previous
//
#include <hip/hip_runtime.h>
#include <math.h>

// Soft-Viterbi structured decoding: B=32, T=512, N=128, fp32.
// Linear-space formulation, ONE barrier + ONE LDS round trip per step,
// no transcendentals on the critical path.
//
// Forward:  alpha~_t = d_t * r_{t-1} * Z_raw,t ;  Z_raw,t[n] = sum_p T[p,n] alpha~_{t-1}[p]
//           d_t = exp(em_t) (prefetched 2 steps ahead, off-chain)
//           r_{t-1} = 1/alpha~_{t-1}[0]  (from broadcast read of ebuf[0], off-chain)
//           alpha~_t stashed into out[b][t] (scratch-in-output), r_t in LDS sarr[].
// Backward: p_t[m] = alpha~_t[m] * sum_n q[n] T[m,n],
//           q[n] = p_{t+1}[n] * d_{t+1}[n] * r_t / alpha~_{t+1}[n]  (all prefetched off-chain).
//
// Layout: 4 waves; wave w owns states [32w,32w+32); lane pair (si=lane>>1, ph=lane&1)
// computes one state's full 128-dot: 64 FMA over half [64ph,64ph+64) + shfl_xor(1) combine.
// e/q exchange ping-pongs ubuf[2][128] so one barrier/step is WAR/RAW-safe.

#define TT 512
#define BB 32
#define NN 128
#define EPSC 1e-10f
#define TINY 1e-33f

__global__ __launch_bounds__(256, 1)
void soft_viterbi_kernel(const float* __restrict__ trans,
                         const float* __restrict__ emis,
                         const float* __restrict__ prior,
                         float* __restrict__ out) {
  const int b    = blockIdx.x;
  const int tid  = threadIdx.x;
  const int w    = tid >> 6;
  const int lane = tid & 63;
  const int si   = lane >> 1;        // state within chunk
  const int ph   = lane & 1;         // which half of the 128-range this lane sums
  const int n_own = 32 * w + si;     // owned state
  const int pbase = 64 * ph;         // start of this lane's 64-element range

  __shared__ __align__(16) float ubuf[2][NN];  // ping-pong alpha~ / q exchange
  __shared__ __align__(16) float sarr[TT];     // sarr[t] = r_t = 1/alpha~_t[0]
  __shared__ __align__(16) float red[NN];      // rowsum, then reduction scratch

  const float* emb = emis + (size_t)b * TT * NN + n_own;  // per-lane emission column
  float* outb = out + (size_t)b * TT * NN;

  // ---- issue early global loads (prior, em[0..3]) ----
  float pr  = fmaxf(prior[n_own], EPSC);
  float em0 = emb[0];
  float eA  = emb[1 * NN];
  float eB  = emb[2 * NN];
  float eC  = emb[3 * NN];

  // ---- row sums of clipped transition ----
  if (tid < NN) {
    const float4* row = (const float4*)(trans + tid * NN);
    float s = 0.f;
    #pragma unroll 8
    for (int j = 0; j < NN / 4; ++j) {
      float4 v = row[j];
      s += fmaxf(v.x, EPSC) + fmaxf(v.y, EPSC) + fmaxf(v.z, EPSC) + fmaxf(v.w, EPSC);
    }
    red[tid] = s;
  }
  __syncthreads();

  // ---- forward fragment: tf[k] = Tn[pbase+k][n_own] ----
  float tf[64];
  #pragma unroll
  for (int k = 0; k < 64; ++k) {
    const int p = pbase + k;
    tf[k] = fmaxf(trans[p * NN + n_own], EPSC) / red[p];
  }
  // ---- backward fragment: tb[k] = Tn[n_own][pbase+k] ----
  float tb[64];
  {
    const float inv = 1.0f / red[n_own];
    const float4* r = (const float4*)(trans + n_own * NN + pbase);
    #pragma unroll
    for (int k = 0; k < 16; ++k) {
      float4 v = r[k];
      tb[4*k+0] = fmaxf(v.x, EPSC) * inv;
      tb[4*k+1] = fmaxf(v.y, EPSC) * inv;
      tb[4*k+2] = fmaxf(v.z, EPSC) * inv;
      tb[4*k+3] = fmaxf(v.w, EPSC) * inv;
    }
  }

  // ---- prior normalization (chunk sum via masked butterfly, combine via red[]) ----
  float vv = ph ? 0.f : pr;
  #pragma unroll
  for (int m = 1; m < 64; m <<= 1) vv += __shfl_xor(vv, m, 64);
  __syncthreads();                 // all tf/tb reads of red[] complete
  if (lane == 0) red[w] = vv;
  __syncthreads();
  const float psum = (red[0] + red[1]) + (red[2] + red[3]);

  // ---- u0 = alpha~_0 ----
  float an = (pr / psum) * __expf(em0);
  if (ph == 0) { ubuf[0][n_own] = an; outb[n_own] = an; }  // stash row 0
  float d_cur = __expf(eA);        // d_1
  float em_h1 = eB;                // em[2]
  float em_h2 = eC;                // em[3]
  float d_last = d_cur;
  __syncthreads();                 // publish ubuf[0]

  // ================= forward =================
  for (int t = 1; t < TT; ++t) {
    const float* rb = ubuf[(t - 1) & 1];
    const float r0 = rb[0];                       // broadcast read, lands early
    const float4* rb4 = (const float4*)(rb + pbase);
    float a0 = 0.f, a1 = 0.f, a2 = 0.f, a3 = 0.f;
    #pragma unroll
    for (int j = 0; j < 16; ++j) {
      float4 ev = rb4[j];
      a0 = fmaf(ev.x, tf[4*j+0], a0);
      a1 = fmaf(ev.y, tf[4*j+1], a1);
      a2 = fmaf(ev.z, tf[4*j+2], a2);
      a3 = fmaf(ev.w, tf[4*j+3], a3);
    }
    const float rinv = 1.0f / r0;                 // off-chain (r0 early)
    const float dsc  = d_cur * rinv;
    if (t == TT - 1) d_last = d_cur;              // keep d_{T-1} for backward init
    d_cur = __expf(em_h1);                        // d_{t+1}, off-chain
    em_h1 = em_h2;
    const int tpre = (t + 3 < TT) ? (t + 3) : (TT - 1);
    em_h2 = emb[tpre * NN];                       // prefetch em[t+3]
    float z = (a0 + a1) + (a2 + a3);
    z += __shfl_xor(z, 1, 64);                    // combine halves (DPP neighbor swap)
    an = dsc * z;                                 // alpha~_t[n_own]
    if (ph == 0) {
      ubuf[t & 1][n_own] = an;
      if (t < TT - 1) outb[t * NN + n_own] = an;  // stash for backward
    }
    if (tid == 0) sarr[t - 1] = rinv;             // r_{t-1}
    __syncthreads();
  }

  // ================= final softmax =================
  float v2 = ph ? 0.f : an;
  #pragma unroll
  for (int m = 1; m < 64; m <<= 1) v2 += __shfl_xor(v2, m, 64);
  if (lane == 0) red[w] = v2;
  __syncthreads();
  const float total = (red[0] + red[1]) + (red[2] + red[3]);
  float p_cur = an / total;                       // p_{T-1}
  if (ph == 0) outb[(TT - 1) * NN + n_own] = p_cur;

  // ---- backward pipeline init (issue loads early) ----
  float ec_cur = outb[(TT - 2) * NN + n_own];     // alpha~_{T-2}
  float ec_h   = outb[(TT - 3) * NN + n_own];     // alpha~_{T-3}
  float em_b1  = emb[(TT - 2) * NN];              // em[T-2]
  float em_b2  = emb[(TT - 3) * NN];              // em[T-3]
  float g_cur  = d_last * sarr[TT - 2] / fmaxf(an, TINY);  // d_{T-1} r_{T-2} / alpha~_{T-1}

  // ================= backward =================
  for (int t = TT - 2; t >= 0; --t) {
    const float q = p_cur * g_cur;
    if (ph == 0) ubuf[t & 1][n_own] = q;
    // off-chain prep for iter t-1:
    const float sr = sarr[(t > 0) ? (t - 1) : 0];
    const float g_next = __expf(em_b1) * sr / fmaxf(ec_cur, TINY);
    em_b1 = em_b2;
    const int tp = (t >= 2) ? (t - 2) : 0;
    em_b2 = emb[tp * NN];
    __syncthreads();
    const float4* qb4 = (const float4*)(ubuf[t & 1] + pbase);
    float a0 = 0.f, a1 = 0.f, a2 = 0.f, a3 = 0.f;
    #pragma unroll
    for (int j = 0; j < 16; ++j) {
      float4 qv = qb4[j];
      a0 = fmaf(qv.x, tb[4*j+0], a0);
      a1 = fmaf(qv.y, tb[4*j+1], a1);
      a2 = fmaf(qv.z, tb[4*j+2], a2);
      a3 = fmaf(qv.w, tb[4*j+3], a3);
    }
    float s = (a0 + a1) + (a2 + a3);
    s += __shfl_xor(s, 1, 64);
    p_cur = ec_cur * s;                           // p_t
    if (ph == 0) outb[t * NN + n_own] = p_cur;
    g_cur  = g_next;
    ec_cur = ec_h;                                // alpha~_{t-1}
    ec_h   = outb[tp * NN + n_own];               // prefetch alpha~_{t-2}
  }
}

extern "C" void kernel_launch(void* const* d_in, const int* in_sizes, int n_in,
                              void* d_out, int out_size, void* d_ws, size_t ws_size,
                              hipStream_t stream) {
  (void)in_sizes; (void)n_in; (void)d_ws; (void)ws_size; (void)out_size;
  const float* trans = (const float*)d_in[0];
  const float* emis  = (const float*)d_in[1];
  const float* prior = (const float*)d_in[2];
  float* out = (float*)d_out;
  soft_viterbi_kernel<<<dim3(BB), dim3(256), 0, stream>>>(trans, emis, prior, out);
}